// Round 8
// baseline (381.601 us; speedup 1.0000x reference)
//
#include <hip/hip_runtime.h>

#define HIST_BITS 12
#define NBINS (1 << HIST_BITS)        // 4096
#define KEY_SHIFT (32 - HIST_BITS)    // 20
#define REP 4                         // LDS histogram replication factor
#define GRID 512
#define BLK 1024

typedef float fx4 __attribute__((ext_vector_type(4)));

// ws layout:
//   [0, 16384)     : unsigned hist[4096]
//   [16384, 16416) : Ctrl (32 B)
//   [16448, ...)   : uint2 candidate list (key, idx)
struct Ctrl {
    long long k;        // number of elements to zero
    long long r1;       // residual rank inside threshold bin (zero first r1)
    int b1;             // threshold bin (-1 => zero nothing)
    unsigned counter;   // candidate list append counter
    unsigned arrive;    // barrier arrival counter
    unsigned flag;      // threshold-ready flag
};

__device__ __forceinline__ unsigned fkey(float f) {
    unsigned u = __float_as_uint(f);
    return (u & 0x80000000u) ? ~u : (u | 0x80000000u);  // monotonic total order
}

// ---------------- K0: zero hist + ctrl (incl. barrier cells) ----------------
__global__ void k_zero(unsigned* __restrict__ hist, Ctrl* __restrict__ ctrl) {
    int i = blockIdx.x * blockDim.x + threadIdx.x;
    if (i < NBINS) hist[i] = 0;
    if (i == 0) {
        ctrl->k = 0; ctrl->r1 = 0; ctrl->b1 = -1;
        ctrl->counter = 0; ctrl->arrive = 0; ctrl->flag = 0;
    }
}

// ---------------- K1: fused hist -> grid-barrier+scan -> apply ----------------
__global__ void __launch_bounds__(BLK, 8)
k_fused(const float* __restrict__ w, const float* __restrict__ mask,
        float* __restrict__ out, long long n, const float* __restrict__ p_ptr,
        unsigned* __restrict__ ghist, Ctrl* __restrict__ ctrl,
        uint2* __restrict__ list, unsigned cap) {
    __shared__ unsigned sh[NBINS * REP];   // 64 KB (phase1 hist; scan part[] aliases it)
    __shared__ int s_last;
    __shared__ int sb1;

    const int tid = threadIdx.x;
    if (tid == 0) s_last = 0;
    for (int i = tid; i < NBINS * REP; i += BLK) sh[i] = 0;
    __syncthreads();

    const long long n4 = n >> 2;
    const fx4* m4 = (const fx4*)mask;
    const long long B = BLK;
    const long long per = (n4 + gridDim.x - 1) / gridDim.x;   // fx4 per block (contiguous tile)
    const long long s0 = (long long)blockIdx.x * per;
    const long long e = (s0 + per < n4) ? s0 + per : n4;

    // ---- phase 1: histogram my tile (4-way replicated LDS, ILP4) ----
    {
        const unsigned r = tid & (REP - 1);
        long long i = s0 + tid;
        for (; i + 3 * B < e; i += 4 * B) {
            fx4 a = m4[i];
            fx4 b = m4[i + B];
            fx4 c = m4[i + 2 * B];
            fx4 d = m4[i + 3 * B];
            atomicAdd(&sh[(fkey(a.x) >> KEY_SHIFT) * REP + r], 1u);
            atomicAdd(&sh[(fkey(a.y) >> KEY_SHIFT) * REP + r], 1u);
            atomicAdd(&sh[(fkey(a.z) >> KEY_SHIFT) * REP + r], 1u);
            atomicAdd(&sh[(fkey(a.w) >> KEY_SHIFT) * REP + r], 1u);
            atomicAdd(&sh[(fkey(b.x) >> KEY_SHIFT) * REP + r], 1u);
            atomicAdd(&sh[(fkey(b.y) >> KEY_SHIFT) * REP + r], 1u);
            atomicAdd(&sh[(fkey(b.z) >> KEY_SHIFT) * REP + r], 1u);
            atomicAdd(&sh[(fkey(b.w) >> KEY_SHIFT) * REP + r], 1u);
            atomicAdd(&sh[(fkey(c.x) >> KEY_SHIFT) * REP + r], 1u);
            atomicAdd(&sh[(fkey(c.y) >> KEY_SHIFT) * REP + r], 1u);
            atomicAdd(&sh[(fkey(c.z) >> KEY_SHIFT) * REP + r], 1u);
            atomicAdd(&sh[(fkey(c.w) >> KEY_SHIFT) * REP + r], 1u);
            atomicAdd(&sh[(fkey(d.x) >> KEY_SHIFT) * REP + r], 1u);
            atomicAdd(&sh[(fkey(d.y) >> KEY_SHIFT) * REP + r], 1u);
            atomicAdd(&sh[(fkey(d.z) >> KEY_SHIFT) * REP + r], 1u);
            atomicAdd(&sh[(fkey(d.w) >> KEY_SHIFT) * REP + r], 1u);
        }
        for (; i < e; i += B) {
            fx4 a = m4[i];
            atomicAdd(&sh[(fkey(a.x) >> KEY_SHIFT) * REP + r], 1u);
            atomicAdd(&sh[(fkey(a.y) >> KEY_SHIFT) * REP + r], 1u);
            atomicAdd(&sh[(fkey(a.z) >> KEY_SHIFT) * REP + r], 1u);
            atomicAdd(&sh[(fkey(a.w) >> KEY_SHIFT) * REP + r], 1u);
        }
        if (blockIdx.x == 0 && tid == 0) {        // n%4 tail
            for (long long t = n4 * 4; t < n; ++t)
                atomicAdd(&ghist[fkey(mask[t]) >> KEY_SHIFT], 1u);
        }
    }
    __syncthreads();
    for (int b = tid; b < NBINS; b += BLK) {
        unsigned s = sh[b * REP] + sh[b * REP + 1] + sh[b * REP + 2] + sh[b * REP + 3];
        if (s) atomicAdd(&ghist[b], s);
    }
    __threadfence();                               // make my hist adds agent-visible
    __syncthreads();

    // ---- grid barrier: last block scans ----
    if (tid == 0) {
        unsigned old = atomicAdd(&ctrl->arrive, 1u);
        if (old == gridDim.x - 1) s_last = 1;
    }
    __syncthreads();

    if (s_last) {
        long long* part = (long long*)sh;          // hist LDS retired; alias for scan
        double p = (double)p_ptr[0];
        long long kk = (long long)((1.0 - p) * (double)n);  // matches python int()
        if (kk < 0) kk = 0;
        if (kk > n) kk = n;
        const int pern = NBINS / BLK;              // 4 bins per thread
        unsigned c0 = __hip_atomic_load(&ghist[tid * pern + 0], __ATOMIC_RELAXED, __HIP_MEMORY_SCOPE_AGENT);
        unsigned c1 = __hip_atomic_load(&ghist[tid * pern + 1], __ATOMIC_RELAXED, __HIP_MEMORY_SCOPE_AGENT);
        unsigned c2 = __hip_atomic_load(&ghist[tid * pern + 2], __ATOMIC_RELAXED, __HIP_MEMORY_SCOPE_AGENT);
        unsigned c3 = __hip_atomic_load(&ghist[tid * pern + 3], __ATOMIC_RELAXED, __HIP_MEMORY_SCOPE_AGENT);
        long long s = (long long)c0 + c1 + c2 + c3;
        part[tid] = s;
        __syncthreads();
        for (int off = 1; off < BLK; off <<= 1) {  // Hillis-Steele inclusive scan
            long long add = (tid >= off) ? part[tid - off] : 0;
            __syncthreads();
            part[tid] += add;
            __syncthreads();
        }
        if (kk >= 1) {
            long long incl = part[tid];
            long long excl = incl - s;
            if (excl < kk && kk <= incl) {
                long long cum = excl;
                unsigned cs[4] = {c0, c1, c2, c3};
                for (int i = 0; i < pern; ++i) {
                    long long c = (long long)cs[i];
                    if (cum < kk && kk <= cum + c) {
                        __hip_atomic_store(&ctrl->b1, tid * pern + i, __ATOMIC_RELAXED, __HIP_MEMORY_SCOPE_AGENT);
                        __hip_atomic_store(&ctrl->r1, kk - cum, __ATOMIC_RELAXED, __HIP_MEMORY_SCOPE_AGENT);
                        break;
                    }
                    cum += c;
                }
            }
        }
        __syncthreads();
        if (tid == 0) {
            __threadfence();
            __hip_atomic_store(&ctrl->flag, 1u, __ATOMIC_RELEASE, __HIP_MEMORY_SCOPE_AGENT);
        }
    }

    // ---- wait for threshold (all blocks, incl. scanner) ----
    if (tid == 0) {
        int t = 0;
        while (__hip_atomic_load(&ctrl->flag, __ATOMIC_ACQUIRE, __HIP_MEMORY_SCOPE_AGENT) == 0u) {
            __builtin_amdgcn_s_sleep(32);
            if (++t > 2000000) break;              // safety valve: fail-loud, never hang
        }
        sb1 = __hip_atomic_load(&ctrl->b1, __ATOMIC_RELAXED, __HIP_MEMORY_SCOPE_AGENT);
    }
    __syncthreads();
    const int b1 = sb1;

    // ---- phase 2: apply over the same tile (mask now L3-resident) ----
    const unsigned b1u = (unsigned)b1;                                  // never matches for b1=-1
    const unsigned lo = (b1 <= 0) ? 0u : ((unsigned)b1 << KEY_SHIFT);   // keep iff key >= lo
    const fx4* w4 = (const fx4*)w;
    fx4* o4 = (fx4*)out;

    long long i = s0 + tid;
    for (; i + 3 * B < e; i += 4 * B) {
        fx4 m0 = m4[i];
        fx4 m1 = m4[i + B];
        fx4 m2 = m4[i + 2 * B];
        fx4 m3 = m4[i + 3 * B];
        fx4 w0 = __builtin_nontemporal_load(&w4[i]);
        fx4 w1 = __builtin_nontemporal_load(&w4[i + B]);
        fx4 w2 = __builtin_nontemporal_load(&w4[i + 2 * B]);
        fx4 w3 = __builtin_nontemporal_load(&w4[i + 3 * B]);
        unsigned k00 = fkey(m0.x), k01 = fkey(m0.y), k02 = fkey(m0.z), k03 = fkey(m0.w);
        unsigned k10 = fkey(m1.x), k11 = fkey(m1.y), k12 = fkey(m1.z), k13 = fkey(m1.w);
        unsigned k20 = fkey(m2.x), k21 = fkey(m2.y), k22 = fkey(m2.z), k23 = fkey(m2.w);
        unsigned k30 = fkey(m3.x), k31 = fkey(m3.y), k32 = fkey(m3.z), k33 = fkey(m3.w);
        fx4 o0, o1, o2, o3;
        o0.x = (k00 >= lo) ? w0.x : 0.0f;  o0.y = (k01 >= lo) ? w0.y : 0.0f;
        o0.z = (k02 >= lo) ? w0.z : 0.0f;  o0.w = (k03 >= lo) ? w0.w : 0.0f;
        o1.x = (k10 >= lo) ? w1.x : 0.0f;  o1.y = (k11 >= lo) ? w1.y : 0.0f;
        o1.z = (k12 >= lo) ? w1.z : 0.0f;  o1.w = (k13 >= lo) ? w1.w : 0.0f;
        o2.x = (k20 >= lo) ? w2.x : 0.0f;  o2.y = (k21 >= lo) ? w2.y : 0.0f;
        o2.z = (k22 >= lo) ? w2.z : 0.0f;  o2.w = (k23 >= lo) ? w2.w : 0.0f;
        o3.x = (k30 >= lo) ? w3.x : 0.0f;  o3.y = (k31 >= lo) ? w3.y : 0.0f;
        o3.z = (k32 >= lo) ? w3.z : 0.0f;  o3.w = (k33 >= lo) ? w3.w : 0.0f;
        __builtin_nontemporal_store(o0, &o4[i]);
        __builtin_nontemporal_store(o1, &o4[i + B]);
        __builtin_nontemporal_store(o2, &o4[i + 2 * B]);
        __builtin_nontemporal_store(o3, &o4[i + 3 * B]);
        bool anyc = ((k00 >> KEY_SHIFT) == b1u) | ((k01 >> KEY_SHIFT) == b1u) |
                    ((k02 >> KEY_SHIFT) == b1u) | ((k03 >> KEY_SHIFT) == b1u) |
                    ((k10 >> KEY_SHIFT) == b1u) | ((k11 >> KEY_SHIFT) == b1u) |
                    ((k12 >> KEY_SHIFT) == b1u) | ((k13 >> KEY_SHIFT) == b1u) |
                    ((k20 >> KEY_SHIFT) == b1u) | ((k21 >> KEY_SHIFT) == b1u) |
                    ((k22 >> KEY_SHIFT) == b1u) | ((k23 >> KEY_SHIFT) == b1u) |
                    ((k30 >> KEY_SHIFT) == b1u) | ((k31 >> KEY_SHIFT) == b1u) |
                    ((k32 >> KEY_SHIFT) == b1u) | ((k33 >> KEY_SHIFT) == b1u);
        if (__any(anyc)) {
            unsigned ks[16] = {k00,k01,k02,k03,k10,k11,k12,k13,k20,k21,k22,k23,k30,k31,k32,k33};
            long long bases[4] = {i, i + B, i + 2 * B, i + 3 * B};
            for (int q = 0; q < 4; ++q)
                for (int j = 0; j < 4; ++j)
                    if ((ks[q * 4 + j] >> KEY_SHIFT) == b1u) {
                        unsigned p = atomicAdd(&ctrl->counter, 1u);
                        if (p < cap) list[p] = make_uint2(ks[q * 4 + j], (unsigned)(bases[q] * 4 + j));
                    }
        }
    }
    for (; i < e; i += B) {
        fx4 m0 = m4[i];
        fx4 w0 = __builtin_nontemporal_load(&w4[i]);
        unsigned k00 = fkey(m0.x), k01 = fkey(m0.y), k02 = fkey(m0.z), k03 = fkey(m0.w);
        fx4 o0;
        o0.x = (k00 >= lo) ? w0.x : 0.0f;  o0.y = (k01 >= lo) ? w0.y : 0.0f;
        o0.z = (k02 >= lo) ? w0.z : 0.0f;  o0.w = (k03 >= lo) ? w0.w : 0.0f;
        __builtin_nontemporal_store(o0, &o4[i]);
        bool anyc = ((k00 >> KEY_SHIFT) == b1u) | ((k01 >> KEY_SHIFT) == b1u) |
                    ((k02 >> KEY_SHIFT) == b1u) | ((k03 >> KEY_SHIFT) == b1u);
        if (__any(anyc)) {
            unsigned ks[4] = {k00, k01, k02, k03};
            for (int j = 0; j < 4; ++j)
                if ((ks[j] >> KEY_SHIFT) == b1u) {
                    unsigned p = atomicAdd(&ctrl->counter, 1u);
                    if (p < cap) list[p] = make_uint2(ks[j], (unsigned)(i * 4 + j));
                }
        }
    }
    if (blockIdx.x == 0 && tid == 0) {             // n%4 tail
        for (long long t = n4 * 4; t < n; ++t) {
            unsigned key = fkey(mask[t]);
            out[t] = (key >= lo) ? w[t] : 0.0f;
            if ((key >> KEY_SHIFT) == b1u) {
                unsigned p = atomicAdd(&ctrl->counter, 1u);
                if (p < cap) list[p] = make_uint2(key, (unsigned)t);
            }
        }
    }
}

// ---------------- K2: exact rank among candidates, zero first r1 ----------------
__global__ void k_fix(float* __restrict__ out, const Ctrl* __restrict__ ctrl,
                      const uint2* __restrict__ list, unsigned cap) {
    __shared__ uint2 ch[1024];
    unsigned nc = ctrl->counter;
    if (nc > cap) nc = cap;
    const long long r1 = ctrl->r1;
    if (ctrl->b1 < 0 || r1 <= 0) return;

    for (unsigned jb = 0; jb < nc; jb += blockDim.x) {
        unsigned j = jb + threadIdx.x;
        bool act = (j < nc);
        unsigned kj = 0, ij = 0;
        if (act) { uint2 e = list[j]; kj = e.x; ij = e.y; }
        long long rank = 0;
        for (unsigned cb = 0; cb < nc; cb += 1024) {
            unsigned mlen = nc - cb; if (mlen > 1024) mlen = 1024;
            for (unsigned u = threadIdx.x; u < mlen; u += blockDim.x) ch[u] = list[cb + u];
            __syncthreads();
            if (act) {
                for (unsigned u = 0; u < mlen; ++u) {
                    uint2 e = ch[u];
                    rank += (long long)((e.x < kj) || (e.x == kj && e.y < ij));
                }
            }
            __syncthreads();
        }
        if (act && rank < r1) out[ij] = 0.0f;
    }
}

extern "C" void kernel_launch(void* const* d_in, const int* in_sizes, int n_in,
                              void* d_out, int out_size, void* d_ws, size_t ws_size,
                              hipStream_t stream) {
    const float* weight = (const float*)d_in[0];
    const float* maskw  = (const float*)d_in[1];
    const float* pptr   = (const float*)d_in[2];
    float* out = (float*)d_out;
    const long long n = (long long)in_sizes[0];

    unsigned char* ws = (unsigned char*)d_ws;
    unsigned* hist = (unsigned*)ws;
    Ctrl* ctrl = (Ctrl*)(ws + 16384);
    uint2* list = (uint2*)(ws + 16448);
    size_t cap_sz = (ws_size > 16448) ? (ws_size - 16448) / sizeof(uint2) : 0;
    unsigned cap = (unsigned)(cap_sz > (size_t)(1u << 20) ? (1u << 20) : cap_sz);

    k_zero<<<(NBINS + 255) / 256, 256, 0, stream>>>(hist, ctrl);
    k_fused<<<GRID, BLK, 0, stream>>>(weight, maskw, out, n, pptr, hist, ctrl, list, cap);
    k_fix<<<1, 1024, 0, stream>>>(out, ctrl, list, cap);
}

// Round 9
// 289.594 us; speedup vs baseline: 1.3177x; 1.3177x over previous
//
#include <hip/hip_runtime.h>

#define HIST_BITS 12
#define NBINS (1 << HIST_BITS)        // 4096
#define KEY_SHIFT (32 - HIST_BITS)    // 20
#define REP 4                         // LDS histogram replication factor
#define GRID 512
#define BLK 512

typedef float fx4 __attribute__((ext_vector_type(4)));

// ws layout:
//   [0, 16384)     : unsigned hist[4096]
//   [16384, 16416) : Ctrl (32 B)
//   [16448, ...)   : uint2 candidate list (key, idx)
struct Ctrl {
    long long k;        // number of elements to zero
    long long r1;       // residual rank inside threshold bin (zero first r1)
    int b1;             // threshold bin (-1 => zero nothing)
    unsigned counter;   // candidate list append counter
    unsigned arrive;    // barrier arrival counter
    unsigned flag;      // threshold-ready flag
};

__device__ __forceinline__ unsigned fkey(float f) {
    unsigned u = __float_as_uint(f);
    return (u & 0x80000000u) ? ~u : (u | 0x80000000u);  // monotonic total order
}

// ---------------- K0: zero hist + ctrl (incl. barrier cells) ----------------
__global__ void k_zero(unsigned* __restrict__ hist, Ctrl* __restrict__ ctrl) {
    int i = blockIdx.x * blockDim.x + threadIdx.x;
    if (i < NBINS) hist[i] = 0;
    if (i == 0) {
        ctrl->k = 0; ctrl->r1 = 0; ctrl->b1 = -1;
        ctrl->counter = 0; ctrl->arrive = 0; ctrl->flag = 0;
    }
}

// ---------------- K1: fused hist -> grid-barrier+scan -> apply ----------------
// __launch_bounds__(512, 4): VGPR cap 128 (R8's (1024,8) forced 32 VGPR -> scratch
// spill -> 381us). 2 blocks/CU co-resident (LDS 128KB/CU), grid 512 == capacity.
__global__ void __launch_bounds__(BLK, 4)
k_fused(const float* __restrict__ w, const float* __restrict__ mask,
        float* __restrict__ out, long long n, const float* __restrict__ p_ptr,
        unsigned* __restrict__ ghist, Ctrl* __restrict__ ctrl,
        uint2* __restrict__ list, unsigned cap) {
    __shared__ unsigned sh[NBINS * REP];   // 64 KB (phase1 hist; scan part[] aliases it)
    __shared__ int s_last;
    __shared__ int sb1;

    const int tid = threadIdx.x;
    if (tid == 0) s_last = 0;
    for (int i = tid; i < NBINS * REP; i += BLK) sh[i] = 0;
    __syncthreads();

    const long long n4 = n >> 2;
    const fx4* m4 = (const fx4*)mask;
    const long long B = BLK;
    const long long per = (n4 + gridDim.x - 1) / gridDim.x;   // fx4 per block (contiguous tile)
    const long long s0 = (long long)blockIdx.x * per;
    const long long e = (s0 + per < n4) ? s0 + per : n4;

    // ---- phase 1: histogram my tile (4-way replicated LDS, ILP4) ----
    {
        const unsigned r = tid & (REP - 1);
        long long i = s0 + tid;
        for (; i + 3 * B < e; i += 4 * B) {
            fx4 a = m4[i];
            fx4 b = m4[i + B];
            fx4 c = m4[i + 2 * B];
            fx4 d = m4[i + 3 * B];
            atomicAdd(&sh[(fkey(a.x) >> KEY_SHIFT) * REP + r], 1u);
            atomicAdd(&sh[(fkey(a.y) >> KEY_SHIFT) * REP + r], 1u);
            atomicAdd(&sh[(fkey(a.z) >> KEY_SHIFT) * REP + r], 1u);
            atomicAdd(&sh[(fkey(a.w) >> KEY_SHIFT) * REP + r], 1u);
            atomicAdd(&sh[(fkey(b.x) >> KEY_SHIFT) * REP + r], 1u);
            atomicAdd(&sh[(fkey(b.y) >> KEY_SHIFT) * REP + r], 1u);
            atomicAdd(&sh[(fkey(b.z) >> KEY_SHIFT) * REP + r], 1u);
            atomicAdd(&sh[(fkey(b.w) >> KEY_SHIFT) * REP + r], 1u);
            atomicAdd(&sh[(fkey(c.x) >> KEY_SHIFT) * REP + r], 1u);
            atomicAdd(&sh[(fkey(c.y) >> KEY_SHIFT) * REP + r], 1u);
            atomicAdd(&sh[(fkey(c.z) >> KEY_SHIFT) * REP + r], 1u);
            atomicAdd(&sh[(fkey(c.w) >> KEY_SHIFT) * REP + r], 1u);
            atomicAdd(&sh[(fkey(d.x) >> KEY_SHIFT) * REP + r], 1u);
            atomicAdd(&sh[(fkey(d.y) >> KEY_SHIFT) * REP + r], 1u);
            atomicAdd(&sh[(fkey(d.z) >> KEY_SHIFT) * REP + r], 1u);
            atomicAdd(&sh[(fkey(d.w) >> KEY_SHIFT) * REP + r], 1u);
        }
        for (; i < e; i += B) {
            fx4 a = m4[i];
            atomicAdd(&sh[(fkey(a.x) >> KEY_SHIFT) * REP + r], 1u);
            atomicAdd(&sh[(fkey(a.y) >> KEY_SHIFT) * REP + r], 1u);
            atomicAdd(&sh[(fkey(a.z) >> KEY_SHIFT) * REP + r], 1u);
            atomicAdd(&sh[(fkey(a.w) >> KEY_SHIFT) * REP + r], 1u);
        }
        if (blockIdx.x == 0 && tid == 0) {        // n%4 tail
            for (long long t = n4 * 4; t < n; ++t)
                atomicAdd(&ghist[fkey(mask[t]) >> KEY_SHIFT], 1u);
        }
    }
    __syncthreads();
    for (int b = tid; b < NBINS; b += BLK) {
        unsigned s = sh[b * REP] + sh[b * REP + 1] + sh[b * REP + 2] + sh[b * REP + 3];
        if (s) atomicAdd(&ghist[b], s);
    }
    __threadfence();                               // make my hist adds agent-visible
    __syncthreads();

    // ---- grid barrier: last block scans ----
    if (tid == 0) {
        unsigned old = atomicAdd(&ctrl->arrive, 1u);
        if (old == gridDim.x - 1) s_last = 1;
    }
    __syncthreads();

    if (s_last) {
        long long* part = (long long*)sh;          // hist LDS retired; alias for scan
        double p = (double)p_ptr[0];
        long long kk = (long long)((1.0 - p) * (double)n);  // matches python int()
        if (kk < 0) kk = 0;
        if (kk > n) kk = n;
        const int pern = NBINS / BLK;              // 8 bins per thread
        unsigned cs[pern];
        long long s = 0;
        #pragma unroll
        for (int i = 0; i < pern; ++i) {
            cs[i] = __hip_atomic_load(&ghist[tid * pern + i], __ATOMIC_RELAXED, __HIP_MEMORY_SCOPE_AGENT);
            s += (long long)cs[i];
        }
        part[tid] = s;
        __syncthreads();
        for (int off = 1; off < BLK; off <<= 1) {  // Hillis-Steele inclusive scan
            long long add = (tid >= off) ? part[tid - off] : 0;
            __syncthreads();
            part[tid] += add;
            __syncthreads();
        }
        if (kk >= 1) {
            long long incl = part[tid];
            long long excl = incl - s;
            if (excl < kk && kk <= incl) {
                long long cum = excl;
                #pragma unroll
                for (int i = 0; i < pern; ++i) {
                    long long c = (long long)cs[i];
                    if (cum < kk && kk <= cum + c) {
                        __hip_atomic_store(&ctrl->b1, tid * pern + i, __ATOMIC_RELAXED, __HIP_MEMORY_SCOPE_AGENT);
                        __hip_atomic_store(&ctrl->r1, kk - cum, __ATOMIC_RELAXED, __HIP_MEMORY_SCOPE_AGENT);
                        break;
                    }
                    cum += c;
                }
            }
        }
        __syncthreads();
        if (tid == 0) {
            __threadfence();
            __hip_atomic_store(&ctrl->flag, 1u, __ATOMIC_RELEASE, __HIP_MEMORY_SCOPE_AGENT);
        }
    }

    // ---- wait for threshold (all blocks, incl. scanner) ----
    if (tid == 0) {
        int t = 0;
        while (__hip_atomic_load(&ctrl->flag, __ATOMIC_ACQUIRE, __HIP_MEMORY_SCOPE_AGENT) == 0u) {
            __builtin_amdgcn_s_sleep(32);
            if (++t > 2000000) break;              // safety valve: fail-loud, never hang
        }
        sb1 = __hip_atomic_load(&ctrl->b1, __ATOMIC_RELAXED, __HIP_MEMORY_SCOPE_AGENT);
    }
    __syncthreads();
    const int b1 = sb1;

    // ---- phase 2: apply over the same tile (mask L3-resident) ----
    const unsigned b1u = (unsigned)b1;                                  // never matches for b1=-1
    const unsigned lo = (b1 <= 0) ? 0u : ((unsigned)b1 << KEY_SHIFT);   // keep iff key >= lo
    const fx4* w4 = (const fx4*)w;
    fx4* o4 = (fx4*)out;

    long long i = s0 + tid;
    for (; i + 3 * B < e; i += 4 * B) {
        fx4 m0 = m4[i];
        fx4 m1 = m4[i + B];
        fx4 m2 = m4[i + 2 * B];
        fx4 m3 = m4[i + 3 * B];
        fx4 w0 = __builtin_nontemporal_load(&w4[i]);
        fx4 w1 = __builtin_nontemporal_load(&w4[i + B]);
        fx4 w2 = __builtin_nontemporal_load(&w4[i + 2 * B]);
        fx4 w3 = __builtin_nontemporal_load(&w4[i + 3 * B]);
        unsigned k00 = fkey(m0.x), k01 = fkey(m0.y), k02 = fkey(m0.z), k03 = fkey(m0.w);
        unsigned k10 = fkey(m1.x), k11 = fkey(m1.y), k12 = fkey(m1.z), k13 = fkey(m1.w);
        unsigned k20 = fkey(m2.x), k21 = fkey(m2.y), k22 = fkey(m2.z), k23 = fkey(m2.w);
        unsigned k30 = fkey(m3.x), k31 = fkey(m3.y), k32 = fkey(m3.z), k33 = fkey(m3.w);
        fx4 o0, o1, o2, o3;
        o0.x = (k00 >= lo) ? w0.x : 0.0f;  o0.y = (k01 >= lo) ? w0.y : 0.0f;
        o0.z = (k02 >= lo) ? w0.z : 0.0f;  o0.w = (k03 >= lo) ? w0.w : 0.0f;
        o1.x = (k10 >= lo) ? w1.x : 0.0f;  o1.y = (k11 >= lo) ? w1.y : 0.0f;
        o1.z = (k12 >= lo) ? w1.z : 0.0f;  o1.w = (k13 >= lo) ? w1.w : 0.0f;
        o2.x = (k20 >= lo) ? w2.x : 0.0f;  o2.y = (k21 >= lo) ? w2.y : 0.0f;
        o2.z = (k22 >= lo) ? w2.z : 0.0f;  o2.w = (k23 >= lo) ? w2.w : 0.0f;
        o3.x = (k30 >= lo) ? w3.x : 0.0f;  o3.y = (k31 >= lo) ? w3.y : 0.0f;
        o3.z = (k32 >= lo) ? w3.z : 0.0f;  o3.w = (k33 >= lo) ? w3.w : 0.0f;
        __builtin_nontemporal_store(o0, &o4[i]);
        __builtin_nontemporal_store(o1, &o4[i + B]);
        __builtin_nontemporal_store(o2, &o4[i + 2 * B]);
        __builtin_nontemporal_store(o3, &o4[i + 3 * B]);
        bool anyc = ((k00 >> KEY_SHIFT) == b1u) | ((k01 >> KEY_SHIFT) == b1u) |
                    ((k02 >> KEY_SHIFT) == b1u) | ((k03 >> KEY_SHIFT) == b1u) |
                    ((k10 >> KEY_SHIFT) == b1u) | ((k11 >> KEY_SHIFT) == b1u) |
                    ((k12 >> KEY_SHIFT) == b1u) | ((k13 >> KEY_SHIFT) == b1u) |
                    ((k20 >> KEY_SHIFT) == b1u) | ((k21 >> KEY_SHIFT) == b1u) |
                    ((k22 >> KEY_SHIFT) == b1u) | ((k23 >> KEY_SHIFT) == b1u) |
                    ((k30 >> KEY_SHIFT) == b1u) | ((k31 >> KEY_SHIFT) == b1u) |
                    ((k32 >> KEY_SHIFT) == b1u) | ((k33 >> KEY_SHIFT) == b1u);
        if (__any(anyc)) {   // rare path: fully unrolled, static indexing
            unsigned ks[16] = {k00,k01,k02,k03,k10,k11,k12,k13,k20,k21,k22,k23,k30,k31,k32,k33};
            long long bases[4] = {i, i + B, i + 2 * B, i + 3 * B};
            #pragma unroll
            for (int q = 0; q < 4; ++q)
                #pragma unroll
                for (int j = 0; j < 4; ++j)
                    if ((ks[q * 4 + j] >> KEY_SHIFT) == b1u) {
                        unsigned p = atomicAdd(&ctrl->counter, 1u);
                        if (p < cap) list[p] = make_uint2(ks[q * 4 + j], (unsigned)(bases[q] * 4 + j));
                    }
        }
    }
    for (; i < e; i += B) {
        fx4 m0 = m4[i];
        fx4 w0 = __builtin_nontemporal_load(&w4[i]);
        unsigned k00 = fkey(m0.x), k01 = fkey(m0.y), k02 = fkey(m0.z), k03 = fkey(m0.w);
        fx4 o0;
        o0.x = (k00 >= lo) ? w0.x : 0.0f;  o0.y = (k01 >= lo) ? w0.y : 0.0f;
        o0.z = (k02 >= lo) ? w0.z : 0.0f;  o0.w = (k03 >= lo) ? w0.w : 0.0f;
        __builtin_nontemporal_store(o0, &o4[i]);
        bool anyc = ((k00 >> KEY_SHIFT) == b1u) | ((k01 >> KEY_SHIFT) == b1u) |
                    ((k02 >> KEY_SHIFT) == b1u) | ((k03 >> KEY_SHIFT) == b1u);
        if (__any(anyc)) {
            unsigned ks[4] = {k00, k01, k02, k03};
            #pragma unroll
            for (int j = 0; j < 4; ++j)
                if ((ks[j] >> KEY_SHIFT) == b1u) {
                    unsigned p = atomicAdd(&ctrl->counter, 1u);
                    if (p < cap) list[p] = make_uint2(ks[j], (unsigned)(i * 4 + j));
                }
        }
    }
    if (blockIdx.x == 0 && tid == 0) {             // n%4 tail
        for (long long t = n4 * 4; t < n; ++t) {
            unsigned key = fkey(mask[t]);
            out[t] = (key >= lo) ? w[t] : 0.0f;
            if ((key >> KEY_SHIFT) == b1u) {
                unsigned p = atomicAdd(&ctrl->counter, 1u);
                if (p < cap) list[p] = make_uint2(key, (unsigned)t);
            }
        }
    }
}

// ---------------- K2: exact rank among candidates, zero first r1 ----------------
__global__ void k_fix(float* __restrict__ out, const Ctrl* __restrict__ ctrl,
                      const uint2* __restrict__ list, unsigned cap) {
    __shared__ uint2 ch[1024];
    unsigned nc = ctrl->counter;
    if (nc > cap) nc = cap;
    const long long r1 = ctrl->r1;
    if (ctrl->b1 < 0 || r1 <= 0) return;

    for (unsigned jb = 0; jb < nc; jb += blockDim.x) {
        unsigned j = jb + threadIdx.x;
        bool act = (j < nc);
        unsigned kj = 0, ij = 0;
        if (act) { uint2 e = list[j]; kj = e.x; ij = e.y; }
        long long rank = 0;
        for (unsigned cb = 0; cb < nc; cb += 1024) {
            unsigned mlen = nc - cb; if (mlen > 1024) mlen = 1024;
            for (unsigned u = threadIdx.x; u < mlen; u += blockDim.x) ch[u] = list[cb + u];
            __syncthreads();
            if (act) {
                for (unsigned u = 0; u < mlen; ++u) {
                    uint2 e = ch[u];
                    rank += (long long)((e.x < kj) || (e.x == kj && e.y < ij));
                }
            }
            __syncthreads();
        }
        if (act && rank < r1) out[ij] = 0.0f;
    }
}

extern "C" void kernel_launch(void* const* d_in, const int* in_sizes, int n_in,
                              void* d_out, int out_size, void* d_ws, size_t ws_size,
                              hipStream_t stream) {
    const float* weight = (const float*)d_in[0];
    const float* maskw  = (const float*)d_in[1];
    const float* pptr   = (const float*)d_in[2];
    float* out = (float*)d_out;
    const long long n = (long long)in_sizes[0];

    unsigned char* ws = (unsigned char*)d_ws;
    unsigned* hist = (unsigned*)ws;
    Ctrl* ctrl = (Ctrl*)(ws + 16384);
    uint2* list = (uint2*)(ws + 16448);
    size_t cap_sz = (ws_size > 16448) ? (ws_size - 16448) / sizeof(uint2) : 0;
    unsigned cap = (unsigned)(cap_sz > (size_t)(1u << 20) ? (1u << 20) : cap_sz);

    k_zero<<<(NBINS + 255) / 256, 256, 0, stream>>>(hist, ctrl);
    k_fused<<<GRID, BLK, 0, stream>>>(weight, maskw, out, n, pptr, hist, ctrl, list, cap);
    k_fix<<<1, 1024, 0, stream>>>(out, ctrl, list, cap);
}